// Round 1
// baseline (414.632 us; speedup 1.0000x reference)
//
#include <hip/hip_runtime.h>
#include <cstdint>
#include <cstddef>

// x = x556 + x570 (fp32 [12544,1024]); LayerNorm over C=1024; y = xn @ W^T + b
// (W [4096,1024] fp32, row-major = B^T GEMM layout); out = gelu(y), fp32.
// Internal compute: bf16 MFMA 32x32x16; tanh-form GELU (|err| vs erf ~1e-3 << 6.4e-2 thr).
#define M_DIM 12544
#define K_DIM 1024
#define N_DIM 4096

typedef __bf16 bf16x8 __attribute__((ext_vector_type(8)));
typedef float f32x16 __attribute__((ext_vector_type(16)));

__device__ __forceinline__ unsigned short bf16_rne(float f) {
    unsigned int u = __float_as_uint(f);
    u += 0x7FFFu + ((u >> 16) & 1u);
    return (unsigned short)(u >> 16);
}
__device__ __forceinline__ unsigned int pack2_bf16(float lo, float hi) {
    return (unsigned int)bf16_rne(lo) | ((unsigned int)bf16_rne(hi) << 16);
}
// tanh-form GELU: x * sigmoid(1.5957691*x*(1+0.044715 x^2)); ~8 VALU ops vs erff's ~25.
__device__ __forceinline__ float gelu_fast(float x) {
    float t = 1.5957691216057308f * x * fmaf(0.044715f, x * x, 1.0f);
    float e = __expf(-t);                       // v_exp_f32
    return x * __builtin_amdgcn_rcpf(1.0f + e); // v_rcp_f32
}

// async global->LDS, 16B per lane. LDS dest must be wave-uniform base + lane*16.
__device__ __forceinline__ void async_load16(const void* g, void* l) {
    __builtin_amdgcn_global_load_lds(
        (const __attribute__((address_space(1))) void*)g,
        (__attribute__((address_space(3))) void*)l,
        16, 0, 0);
}

// ---------------- residual add + LayerNorm (fp32 in) -> bf16 xn ----------------
__global__ __launch_bounds__(256) void ln_fused(
    const float* __restrict__ x0,
    const float* __restrict__ x1,
    const float* __restrict__ gam,
    const float* __restrict__ bet,
    unsigned short* __restrict__ o)
{
    const int lane = threadIdx.x & 63;
    const int wv   = threadIdx.x >> 6;
    const size_t row = (size_t)blockIdx.x * 4 + wv;
    const float* p0 = x0 + row * K_DIM;
    const float* p1 = x1 + row * K_DIM;

    float v[16];
    #pragma unroll
    for (int i = 0; i < 4; ++i) {
        float4 a = *(const float4*)(p0 + i * 256 + lane * 4);
        float4 b = *(const float4*)(p1 + i * 256 + lane * 4);
        v[4*i+0] = a.x + b.x; v[4*i+1] = a.y + b.y;
        v[4*i+2] = a.z + b.z; v[4*i+3] = a.w + b.w;
    }

    float s = 0.f, sq = 0.f;
    #pragma unroll
    for (int i = 0; i < 16; ++i) { s += v[i]; sq += v[i] * v[i]; }
    #pragma unroll
    for (int m = 32; m >= 1; m >>= 1) {
        s  += __shfl_xor(s,  m);
        sq += __shfl_xor(sq, m);
    }
    const float mean = s * (1.0f / 1024.0f);
    float var = sq * (1.0f / 1024.0f) - mean * mean;
    var = fmaxf(var, 0.0f);
    const float rstd = rsqrtf(var + 1e-5f);

    unsigned short* po = o + row * K_DIM;
    #pragma unroll
    for (int i = 0; i < 4; ++i) {
        float4 g  = *(const float4*)(gam + i * 256 + lane * 4);
        float4 be = *(const float4*)(bet + i * 256 + lane * 4);
        float y0 = (v[4*i+0] - mean) * rstd * g.x + be.x;
        float y1 = (v[4*i+1] - mean) * rstd * g.y + be.y;
        float y2 = (v[4*i+2] - mean) * rstd * g.z + be.z;
        float y3 = (v[4*i+3] - mean) * rstd * g.w + be.w;
        uint2 r;
        r.x = pack2_bf16(y0, y1);
        r.y = pack2_bf16(y2, y3);
        *(uint2*)(po + i * 256 + lane * 4) = r;
    }
}

// ---------------- W fp32 -> bf16 ----------------
__global__ __launch_bounds__(256) void w_to_bf16(
    const float* __restrict__ w, unsigned short* __restrict__ o)
{
    const size_t i = ((size_t)blockIdx.x * 256 + threadIdx.x) * 4;
    float4 v = *(const float4*)(w + i);
    uint2 r;
    r.x = pack2_bf16(v.x, v.y);
    r.y = pack2_bf16(v.z, v.w);
    *(uint2*)(o + i) = r;
}

// ---------------- GEMM: C[M,N] = gelu(A[M,K] @ B[N,K]^T + bias) ----------------
// 128x128 tile, BK=32, 4 waves each 64x64 via 2x2 of mfma_f32_32x32x16_bf16.
// Changes vs prior version:
//  (1) T3-minimum 2-phase: double-buffered LDS, STAGE(t+1) issued BEFORE
//      compute(t), ONE barrier per K-tile. The compiler's vmcnt(0) drain at the
//      barrier now lands AFTER a full ds_read+MFMA phase instead of immediately
//      after issue -> load latency hidden under compute.
//  (2) Period-8 seg swizzle: phys seg = (logical + (row>>1)) & 3. The old
//      (logical+row)&3 had period 4, so each 16-lane b128 group hit only 4 of 8
//      16B slot-classes (2x LDS serialization); period 8 covers all 8 evenly.
//      Swizzle applied on the GLOBAL source (global_load_lds dest stays linear,
//      rule: both-sides-or-neither) and inverted on the fragment ds_read.
__global__ __launch_bounds__(256) void gemm_bias_gelu(
    const unsigned short* __restrict__ A,    // xn [M,K] bf16
    const unsigned short* __restrict__ B,    // W  [N,K] bf16
    const float* __restrict__ bias,          // [N] fp32
    float* __restrict__ C)                   // [M,N] fp32
{
    __shared__ __align__(16) unsigned short At[2][128 * 32];
    __shared__ __align__(16) unsigned short Bt[2][128 * 32];

    const int t  = threadIdx.x;
    const int bn = blockIdx.x;   // 0..31
    const int bm = blockIdx.y;   // 0..97
    const int m0 = bm * 128, n0 = bn * 128;

    // staging: thread t fills LDS slot t (row t>>2, phys seg t&3); global
    // logical seg = (phys - (row>>1)) & 3   [period-8 swizzle]
    const int srow = t >> 2;
    const int gseg = ((t & 3) - (srow >> 1)) & 3;
    const unsigned short* ag0 = A + (size_t)(m0 + srow) * K_DIM + gseg * 8;
    const unsigned short* ag1 = A + (size_t)(m0 + srow + 64) * K_DIM + gseg * 8;
    const unsigned short* bg0 = B + (size_t)(n0 + srow) * K_DIM + gseg * 8;
    const unsigned short* bg1 = B + (size_t)(n0 + srow + 64) * K_DIM + gseg * 8;

    const int lane = t & 63;
    const int w    = t >> 6;
    const int wm   = (w >> 1) * 64;   // wave m-offset in tile
    const int wn   = (w & 1) * 64;    // wave n-offset in tile
    const int ml   = lane & 31;
    const int h    = lane >> 5;

    f32x16 acc[2][2] = {};

    // issue the 4 async loads for the next K-tile into buffer b, advance ptrs
    auto stage = [&](int b) {
        async_load16(ag0, &At[b][t * 8]);
        async_load16(ag1, &At[b][(t + 256) * 8]);
        async_load16(bg0, &Bt[b][t * 8]);
        async_load16(bg1, &Bt[b][(t + 256) * 8]);
        ag0 += 32; ag1 += 32; bg0 += 32; bg1 += 32;
    };

    // fragments: operand [dim=lane&31][k=h*8+j], logical seg l = kk*2+h,
    // phys seg = (l + (row>>1)) & 3
    auto compute = [&](int b) {
        bf16x8 af[2][2], bfr[2][2];
        #pragma unroll
        for (int i = 0; i < 2; ++i)
            #pragma unroll
            for (int kk = 0; kk < 2; ++kk) {
                const int ra = wm + i * 32 + ml;
                const int rb = wn + i * 32 + ml;
                af[i][kk]  = *(const bf16x8*)&At[b][ra * 32 + ((((kk * 2 + h) + (ra >> 1)) & 3) * 8)];
                bfr[i][kk] = *(const bf16x8*)&Bt[b][rb * 32 + ((((kk * 2 + h) + (rb >> 1)) & 3) * 8)];
            }
        #pragma unroll
        for (int kk = 0; kk < 2; ++kk)
            #pragma unroll
            for (int i = 0; i < 2; ++i)
                #pragma unroll
                for (int j = 0; j < 2; ++j)
                    acc[i][j] = __builtin_amdgcn_mfma_f32_32x32x16_bf16(
                        af[i][kk], bfr[j][kk], acc[i][j], 0, 0, 0);
    };

    // prologue: tile 0 -> buf 0
    stage(0);
    __syncthreads();                 // drains vmcnt(0): tile 0 resident

    // main loop: 32 K-tiles total; tile k lives in buf (k&1).
    // each half-iter: issue next-tile loads, compute current, ONE barrier.
    #pragma unroll 1
    for (int kb = 0; kb < 15; ++kb) {
        stage(1); compute(0); __syncthreads();
        stage(0); compute(1); __syncthreads();
    }
    stage(1); compute(0); __syncthreads();   // tile 30 compute, tile 31 staged
    compute(1);                              // tile 31

    // epilogue: C/D layout col=lane&31, row=(reg&3)+8*(reg>>2)+4*h
    #pragma unroll
    for (int j = 0; j < 2; ++j) {
        const int n = n0 + wn + j * 32 + ml;
        const float bj = bias[n];
        #pragma unroll
        for (int i = 0; i < 2; ++i) {
            const int mbase = m0 + wm + i * 32 + 4 * h;
            #pragma unroll
            for (int reg = 0; reg < 16; ++reg) {
                const int m = mbase + (reg & 3) + 8 * (reg >> 2);
                C[(size_t)m * N_DIM + n] = gelu_fast(acc[i][j][reg] + bj);
            }
        }
    }
}

extern "C" void kernel_launch(void* const* d_in, const int* in_sizes, int n_in,
                              void* d_out, int out_size, void* d_ws, size_t ws_size,
                              hipStream_t stream) {
    const float* x556 = (const float*)d_in[0];
    const float* x570 = (const float*)d_in[1];
    const float* gam  = (const float*)d_in[2];
    const float* bet  = (const float*)d_in[3];
    const float* Wlin = (const float*)d_in[4];
    const float* blin = (const float*)d_in[5];
    float* out = (float*)d_out;

    unsigned short* xn = (unsigned short*)d_ws;            // 25.69 MB
    unsigned short* wb = xn + (size_t)M_DIM * K_DIM;       // 8.39 MB

    ln_fused<<<M_DIM / 4, 256, 0, stream>>>(x556, x570, gam, bet, xn);
    w_to_bf16<<<(N_DIM * K_DIM / 4) / 256, 256, 0, stream>>>(Wlin, wb);
    gemm_bias_gelu<<<dim3(N_DIM / 128, M_DIM / 128), 256, 0, stream>>>(xn, wb, blin, out);
}

// Round 3
// 407.584 us; speedup vs baseline: 1.0173x; 1.0173x over previous
//
#include <hip/hip_runtime.h>
#include <cstdint>
#include <cstddef>

// x = x556 + x570 (fp32 [12544,1024]); LayerNorm over C=1024; y = xn @ W^T + b
// (W [4096,1024] fp32, row-major = B^T GEMM layout); out = gelu(y), fp32.
// Internal compute: bf16 MFMA 32x32x16; tanh-form GELU (|err| vs erf ~1e-3 << 6.4e-2 thr).
#define M_DIM 12544
#define K_DIM 1024
#define N_DIM 4096

typedef __bf16 bf16x8 __attribute__((ext_vector_type(8)));
typedef float f32x16 __attribute__((ext_vector_type(16)));

// Counted vmcnt (T4): loads stay in flight across raw s_barriers.
// CLOSING-BARRIER DISCIPLINE (round-2 bug fix): raw s_barrier does NOT drain
// lgkmcnt; a wave could arrive with slot ds_reads still in flight and the next
// ring-step's global_load_lds would overwrite the slot mid-read. Every closing
// barrier is now  lgkmcnt(0) -> sched_barrier(0) -> s_barrier  (ISA §8:
// "s_waitcnt first if data dep"); sched_barrier(0) also pins register-only
// MFMAs from being scheduled across the phase boundary (rule #18).
#define VMCNT(n)  asm volatile("s_waitcnt vmcnt(" #n ")" ::: "memory")
#define LGKMCNT0() asm volatile("s_waitcnt lgkmcnt(0)" ::: "memory")
#define FENCE()   asm volatile("" ::: "memory")
#define SCHED0()  __builtin_amdgcn_sched_barrier(0)
#define BAR()     __builtin_amdgcn_s_barrier()

__device__ __forceinline__ unsigned short bf16_rne(float f) {
    unsigned int u = __float_as_uint(f);
    u += 0x7FFFu + ((u >> 16) & 1u);
    return (unsigned short)(u >> 16);
}
__device__ __forceinline__ unsigned int pack2_bf16(float lo, float hi) {
    return (unsigned int)bf16_rne(lo) | ((unsigned int)bf16_rne(hi) << 16);
}
// tanh-form GELU: x * sigmoid(1.5957691*x*(1+0.044715 x^2)); ~8 VALU ops vs erff's ~25.
__device__ __forceinline__ float gelu_fast(float x) {
    float t = 1.5957691216057308f * x * fmaf(0.044715f, x * x, 1.0f);
    float e = __expf(-t);                       // v_exp_f32
    return x * __builtin_amdgcn_rcpf(1.0f + e); // v_rcp_f32
}

// async global->LDS, 16B per lane. LDS dest must be wave-uniform base + lane*16.
__device__ __forceinline__ void async_load16(const void* g, void* l) {
    __builtin_amdgcn_global_load_lds(
        (const __attribute__((address_space(1))) void*)g,
        (__attribute__((address_space(3))) void*)l,
        16, 0, 0);
}

// -------- fused: residual add + LayerNorm -> bf16 xn  AND  W fp32 -> bf16 ----
// blocks [0,3136): LN rows (4 rows/block). blocks [3136,4160): W convert.
__global__ __launch_bounds__(256) void pre_fused(
    const float* __restrict__ x0,
    const float* __restrict__ x1,
    const float* __restrict__ gam,
    const float* __restrict__ bet,
    const float* __restrict__ Wlin,
    unsigned short* __restrict__ o,
    unsigned short* __restrict__ wb)
{
    const int bid = blockIdx.x;
    if (bid >= M_DIM / 4) {
        // W conversion: 1024 blocks x 256 threads x 16 elems = 4096*1024
        const int wbid = bid - M_DIM / 4;
        const float* wp = Wlin + (size_t)wbid * 4096;
        unsigned short* op = wb + (size_t)wbid * 4096;
        #pragma unroll
        for (int j = 0; j < 4; ++j) {
            float4 v = *(const float4*)(wp + j * 1024 + threadIdx.x * 4);
            uint2 r;
            r.x = pack2_bf16(v.x, v.y);
            r.y = pack2_bf16(v.z, v.w);
            *(uint2*)(op + j * 1024 + threadIdx.x * 4) = r;
        }
        return;
    }

    const int lane = threadIdx.x & 63;
    const int wv   = threadIdx.x >> 6;
    const size_t row = (size_t)bid * 4 + wv;
    const float* p0 = x0 + row * K_DIM;
    const float* p1 = x1 + row * K_DIM;

    float v[16];
    #pragma unroll
    for (int i = 0; i < 4; ++i) {
        float4 a = *(const float4*)(p0 + i * 256 + lane * 4);
        float4 b = *(const float4*)(p1 + i * 256 + lane * 4);
        v[4*i+0] = a.x + b.x; v[4*i+1] = a.y + b.y;
        v[4*i+2] = a.z + b.z; v[4*i+3] = a.w + b.w;
    }

    float s = 0.f, sq = 0.f;
    #pragma unroll
    for (int i = 0; i < 16; ++i) { s += v[i]; sq += v[i] * v[i]; }
    #pragma unroll
    for (int m = 32; m >= 1; m >>= 1) {
        s  += __shfl_xor(s,  m);
        sq += __shfl_xor(sq, m);
    }
    const float mean = s * (1.0f / 1024.0f);
    float var = sq * (1.0f / 1024.0f) - mean * mean;
    var = fmaxf(var, 0.0f);
    const float rstd = rsqrtf(var + 1e-5f);

    unsigned short* po = o + row * K_DIM;
    #pragma unroll
    for (int i = 0; i < 4; ++i) {
        float4 g  = *(const float4*)(gam + i * 256 + lane * 4);
        float4 be = *(const float4*)(bet + i * 256 + lane * 4);
        float y0 = (v[4*i+0] - mean) * rstd * g.x + be.x;
        float y1 = (v[4*i+1] - mean) * rstd * g.y + be.y;
        float y2 = (v[4*i+2] - mean) * rstd * g.z + be.z;
        float y3 = (v[4*i+3] - mean) * rstd * g.w + be.w;
        uint2 r;
        r.x = pack2_bf16(y0, y1);
        r.y = pack2_bf16(y2, y3);
        *(uint2*)(po + i * 256 + lane * 4) = r;
    }
}

// ---------------- GEMM: C[M,N] = gelu(A[M,K] @ B[N,K]^T + bias) ----------------
// 128x128 tile, BK=32, 4 waves each 64x64 via 2x2 of mfma_f32_32x32x16_bf16.
// T4 deep pipeline: 3-slot LDS ring (48 KB -> 3 blocks/CU). Per K-tile t:
//   stage(t+2 -> slot (t+2)%3)       // slot sealed by step t-1's closing phase
//   VMCNT(8); BAR                    // drains exactly tile t's 4 loads (per
//                                    // wave) + aligns all waves -> tile t ready
//   compute(t from slot t%3)
//   LGKMCNT0; SCHED0; BAR            // ALL this wave's ds_reads complete before
//                                    // anyone may overwrite slot t (round-2 fix)
__global__ __launch_bounds__(256) void gemm_bias_gelu(
    const unsigned short* __restrict__ A,    // xn [M,K] bf16
    const unsigned short* __restrict__ B,    // W  [N,K] bf16
    const float* __restrict__ bias,          // [N] fp32
    float* __restrict__ C)                   // [M,N] fp32
{
    __shared__ __align__(16) unsigned short At[3][128 * 32];
    __shared__ __align__(16) unsigned short Bt[3][128 * 32];

    const int t  = threadIdx.x;
    const int bn = blockIdx.x;   // 0..31
    const int bm = blockIdx.y;   // 0..97
    const int m0 = bm * 128, n0 = bn * 128;

    // staging: thread t fills LDS slot t (row t>>2, phys seg t&3); global
    // logical seg = (phys - (row>>1)) & 3   [period-8 swizzle]
    const int srow = t >> 2;
    const int gseg = ((t & 3) - (srow >> 1)) & 3;
    const unsigned short* ag0 = A + (size_t)(m0 + srow) * K_DIM + gseg * 8;
    const unsigned short* ag1 = A + (size_t)(m0 + srow + 64) * K_DIM + gseg * 8;
    const unsigned short* bg0 = B + (size_t)(n0 + srow) * K_DIM + gseg * 8;
    const unsigned short* bg1 = B + (size_t)(n0 + srow + 64) * K_DIM + gseg * 8;

    const int lane = t & 63;
    const int w    = t >> 6;
    const int wm   = (w >> 1) * 64;   // wave m-offset in tile
    const int wn   = (w & 1) * 64;    // wave n-offset in tile
    const int ml   = lane & 31;
    const int h    = lane >> 5;

    f32x16 acc[2][2] = {};

    // issue 4 async loads for the next K-tile into ring slot s, advance ptrs
    auto stage = [&](int s) {
        async_load16(ag0, &At[s][t * 8]);
        async_load16(ag1, &At[s][(t + 256) * 8]);
        async_load16(bg0, &Bt[s][t * 8]);
        async_load16(bg1, &Bt[s][(t + 256) * 8]);
        ag0 += 32; ag1 += 32; bg0 += 32; bg1 += 32;
    };

    // fragments: operand [dim=lane&31][k=h*8+j], logical seg l = kk*2+h,
    // phys seg = (l + (row>>1)) & 3
    auto compute = [&](int s) {
        bf16x8 af[2][2], bfr[2][2];
        #pragma unroll
        for (int i = 0; i < 2; ++i)
            #pragma unroll
            for (int kk = 0; kk < 2; ++kk) {
                const int ra = wm + i * 32 + ml;
                const int rb = wn + i * 32 + ml;
                af[i][kk]  = *(const bf16x8*)&At[s][ra * 32 + ((((kk * 2 + h) + (ra >> 1)) & 3) * 8)];
                bfr[i][kk] = *(const bf16x8*)&Bt[s][rb * 32 + ((((kk * 2 + h) + (rb >> 1)) & 3) * 8)];
            }
        #pragma unroll
        for (int kk = 0; kk < 2; ++kk)
            #pragma unroll
            for (int i = 0; i < 2; ++i)
                #pragma unroll
                for (int j = 0; j < 2; ++j)
                    acc[i][j] = __builtin_amdgcn_mfma_f32_32x32x16_bf16(
                        af[i][kk], bfr[j][kk], acc[i][j], 0, 0, 0);
    };

    // one pipeline step: stage tile t+2 into slot s2, compute tile t from s0
    auto step = [&](int s2, int s0) {
        stage(s2); FENCE();
        VMCNT(8); BAR(); SCHED0();
        compute(s0);
        LGKMCNT0(); SCHED0(); BAR();
    };

    // prologue: stage tiles 0,1 (8 loads in flight)
    stage(0); stage(1); FENCE();

    // 32 K-tiles: tiles 0..29 in the steady loop (10 x 3 ring steps), 30..31 tail.
    #pragma unroll 1
    for (int it = 0; it < 10; ++it) {
        step(2, 0);
        step(0, 1);
        step(1, 2);
    }
    // tail: tile 30 (slot 0) — only tile 31's 4 loads may stay in flight
    VMCNT(4); BAR(); SCHED0();
    compute(0);
    LGKMCNT0(); SCHED0();
    // tile 31 (slot 1) — full drain; BAR so all waves' tile-31 loads landed
    VMCNT(0); BAR(); SCHED0();
    compute(1);

    // epilogue: C/D layout col=lane&31, row=(reg&3)+8*(reg>>2)+4*h
    #pragma unroll
    for (int j = 0; j < 2; ++j) {
        const int n = n0 + wn + j * 32 + ml;
        const float bj = bias[n];
        #pragma unroll
        for (int i = 0; i < 2; ++i) {
            const int mbase = m0 + wm + i * 32 + 4 * h;
            #pragma unroll
            for (int reg = 0; reg < 16; ++reg) {
                const int m = mbase + (reg & 3) + 8 * (reg >> 2);
                C[(size_t)m * N_DIM + n] = gelu_fast(acc[i][j][reg] + bj);
            }
        }
    }
}

extern "C" void kernel_launch(void* const* d_in, const int* in_sizes, int n_in,
                              void* d_out, int out_size, void* d_ws, size_t ws_size,
                              hipStream_t stream) {
    const float* x556 = (const float*)d_in[0];
    const float* x570 = (const float*)d_in[1];
    const float* gam  = (const float*)d_in[2];
    const float* bet  = (const float*)d_in[3];
    const float* Wlin = (const float*)d_in[4];
    const float* blin = (const float*)d_in[5];
    float* out = (float*)d_out;

    unsigned short* xn = (unsigned short*)d_ws;            // 25.69 MB
    unsigned short* wb = xn + (size_t)M_DIM * K_DIM;       // 8.39 MB

    pre_fused<<<M_DIM / 4 + 1024, 256, 0, stream>>>(x556, x570, gam, bet, Wlin, xn, wb);
    gemm_bias_gelu<<<dim3(N_DIM / 128, M_DIM / 128), 256, 0, stream>>>(xn, wb, blin, out);
}